// Round 1
// baseline (2847.306 us; speedup 1.0000x reference)
//
#include <hip/hip_runtime.h>

// DSTP-RNN: B=1024, T_ENC=48, T_DEC+6=30 decoder steps, H=128, F=17 features.
// Persistent kernel: 256 blocks x 512 threads, each block owns 4 batch rows.
// All recurrent state + attention precomputes in LDS; big per-batch tensors
// (pre2, fin) and transposed weights in d_ws.

#define T_ENC 48
#define H 128
#define FDIM 17
#define BBLK 4
#define NTH 512

// ---- ws float offsets ----
#define OFF_WT1   0          // 148*512 = 75776   (e1 gate weights, [k4][j][4], K padded 145->148)
#define OFF_WT2   75776      // 260*512 = 133120  (e2, K padded 257->260)
#define OFF_WTD   208896     // 256*512 = 131072  (dec, K=256)
#define OFF_WE1T  339968     // 256*48  = 12288   (We1^T [k][s])
#define OFF_WE2T  352256     // 256*48  = 12288
#define OFF_WDT   364544     // 256*128 = 32768   (Wd^T [k][s])
#define OFF_UDT   397312     // 128*128 = 16384   (Ud^T [k][h])
#define OFF_B1    413696     // 512 combined biases
#define OFF_B2    414208
#define OFF_BD    414720
#define OFF_PRE2  415232     // 1024*48*129 = 6340608, layout [b][s][f]
#define OFF_FIN   6755840    // 1024*48*128 = 6291456, layout [b][t][h]
#define WS_FLOATS 13047296   // ~52.2 MB

__device__ __forceinline__ float fast_sigm(float x){
    return __fdividef(1.0f, 1.0f + __expf(-x));
}
__device__ __forceinline__ float fast_tanh(float x){
    float xc = fminf(fmaxf(x, -9.0f), 9.0f);
    float e = __expf(2.0f * xc);
    return __fdividef(e - 1.0f, e + 1.0f);
}

// ---------------- prologue: transpose/fuse weights into ws ----------------
__global__ void prep_kernel(const float* __restrict__ We1W, const float* __restrict__ We2W,
                            const float* __restrict__ WdW,  const float* __restrict__ UdW,
                            const float* __restrict__ e1Wih, const float* __restrict__ e1Whh,
                            const float* __restrict__ e1bih, const float* __restrict__ e1bhh,
                            const float* __restrict__ e2Wih, const float* __restrict__ e2Whh,
                            const float* __restrict__ e2bih, const float* __restrict__ e2bhh,
                            const float* __restrict__ dWih,  const float* __restrict__ dWhh,
                            const float* __restrict__ dbih,  const float* __restrict__ dbhh,
                            float* __restrict__ ws)
{
    int idx = blockIdx.x * blockDim.x + threadIdx.x;
    if (idx < 75776) {                       // WT1: [k4][j][4], k<17: Wih, k<145: Whh, else 0
        int k4 = idx >> 11, r = idx & 2047, j = r >> 2, kq = r & 3, k = k4*4 + kq;
        float v = 0.f;
        if (k < 17) v = e1Wih[j*17 + k]; else if (k < 145) v = e1Whh[j*128 + (k-17)];
        ws[OFF_WT1 + idx] = v; return;
    }
    idx -= 75776;
    if (idx < 133120) {                      // WT2: k<129: Wih, k<257: Whh
        int k4 = idx >> 11, r = idx & 2047, j = r >> 2, kq = r & 3, k = k4*4 + kq;
        float v = 0.f;
        if (k < 129) v = e2Wih[j*129 + k]; else if (k < 257) v = e2Whh[j*128 + (k-129)];
        ws[OFF_WT2 + idx] = v; return;
    }
    idx -= 133120;
    if (idx < 131072) {                      // WTD: k<128: Wih, else Whh
        int k4 = idx >> 11, r = idx & 2047, j = r >> 2, kq = r & 3, k = k4*4 + kq;
        float v = (k < 128) ? dWih[j*128 + k] : dWhh[j*128 + (k-128)];
        ws[OFF_WTD + idx] = v; return;
    }
    idx -= 131072;
    if (idx < 12288) { int k = idx/48, s = idx%48; ws[OFF_WE1T + idx] = We1W[s*256 + k]; return; }
    idx -= 12288;
    if (idx < 12288) { int k = idx/48, s = idx%48; ws[OFF_WE2T + idx] = We2W[s*256 + k]; return; }
    idx -= 12288;
    if (idx < 32768) { int k = idx>>7, s = idx&127; ws[OFF_WDT + idx] = WdW[s*256 + k]; return; }
    idx -= 32768;
    if (idx < 16384) { int k = idx>>7, hh = idx&127; ws[OFF_UDT + idx] = UdW[hh*128 + k]; return; }
    idx -= 16384;
    if (idx < 512) { ws[OFF_B1 + idx] = e1bih[idx] + e1bhh[idx]; return; }
    idx -= 512;
    if (idx < 512) { ws[OFF_B2 + idx] = e2bih[idx] + e2bhh[idx]; return; }
    idx -= 512;
    if (idx < 512) { ws[OFF_BD + idx] = dbih[idx] + dbhh[idx]; return; }
}

// gate matmul: g[b][j] = bias[j] + sum_k u[b][k] * W[k][j], 4 batches, j = tid
template<int K4>
__device__ __forceinline__ void lstm_gates(const float4* __restrict__ W4,
                                           const float* __restrict__ bias,
                                           const float* u, float* g, int tid)
{
    float bb = bias[tid];
    float a0 = bb, a1 = bb, a2 = bb, a3 = bb;
    #pragma unroll 4
    for (int k4 = 0; k4 < K4; ++k4) {
        float4 w  = W4[k4*512 + tid];
        float4 ua = *(const float4*)(u +        4*k4);
        float4 ub = *(const float4*)(u + 260 +  4*k4);
        float4 uc = *(const float4*)(u + 520 +  4*k4);
        float4 ud = *(const float4*)(u + 780 +  4*k4);
        a0 = fmaf(w.w, ua.w, fmaf(w.z, ua.z, fmaf(w.y, ua.y, fmaf(w.x, ua.x, a0))));
        a1 = fmaf(w.w, ub.w, fmaf(w.z, ub.z, fmaf(w.y, ub.y, fmaf(w.x, ub.x, a1))));
        a2 = fmaf(w.w, uc.w, fmaf(w.z, uc.z, fmaf(w.y, uc.y, fmaf(w.x, uc.x, a2))));
        a3 = fmaf(w.w, ud.w, fmaf(w.z, ud.z, fmaf(w.y, ud.y, fmaf(w.x, ud.x, a3))));
    }
    g[tid] = a0; g[512 + tid] = a1; g[1024 + tid] = a2; g[1536 + tid] = a3;
}

// softmax over n entries per batch row, 32 threads per b (tid<128), stride 129
__device__ __forceinline__ void softmax4(float* sc, float* at, int n, int tid)
{
    if (tid < 128) {
        int b = tid >> 5, i = tid & 31, base = b*129;
        float m = -1e30f;
        for (int f = i; f < n; f += 32) m = fmaxf(m, sc[base + f]);
        for (int o = 16; o; o >>= 1) m = fmaxf(m, __shfl_xor(m, o, 32));
        float ssum = 0.f;
        for (int f = i; f < n; f += 32) { float p = __expf(sc[base+f] - m); at[base+f] = p; ssum += p; }
        for (int o = 16; o; o >>= 1) ssum += __shfl_xor(ssum, o, 32);
        float inv = __fdividef(1.f, ssum);
        for (int f = i; f < n; f += 32) at[base + f] *= inv;
    }
}

__global__ __launch_bounds__(NTH, 1)
void dstp_main(const float* __restrict__ ipq,  const float* __restrict__ labp,
               const float* __restrict__ Ue1W, const float* __restrict__ Ue1b,
               const float* __restrict__ Ve1,  const float* __restrict__ Ve1b,
               const float* __restrict__ Ue2W, const float* __restrict__ Ue2b,
               const float* __restrict__ Ve2,  const float* __restrict__ Ve2b,
               const float* __restrict__ Udb,
               const float* __restrict__ Vd,   const float* __restrict__ Vdb,
               const float* __restrict__ regW, const float* __restrict__ regb,
               float* __restrict__ ws, float* __restrict__ out)
{
    extern __shared__ float sm[];
    float* sh_h   = sm;            // 512   h[4][128]
    float* sh_c   = sm + 512;      // 512
    float* sh_we  = sm + 1024;     // 512   we/wd scratch
    float* sh_sc  = sm + 1536;     // 516   scores, stride 129
    float* sh_at  = sm + 2052;     // 516   attention weights
    float* sh_g   = sm + 2568;     // 2048  gates [4][512]
    float* sh_u   = sm + 4616;     // 1040  gate input [4][260] (16B aligned)
    float* sh_x   = sm + 5656;     // 3264  x[4][48][17]
    float* sh_p1  = sm + 8920;     // 3264  pre1 [b][s][f]
    float* sh_big = sm + 12184;    // 24768 mid [b][t][129] then ud [b][t][128 of 129]
    // total 36952 floats = 147,808 B

    const int tid = threadIdx.x;
    const int b0  = blockIdx.x * BBLK;

    // ---- phase 0: load x, labels; init h,c; compute pre1 ----
    for (int idx = tid; idx < BBLK*T_ENC*FDIM; idx += NTH) {
        int b = idx / (T_ENC*FDIM), r = idx % (T_ENC*FDIM), t = r / FDIM, f = r % FDIM;
        sh_x[(b*T_ENC + t)*FDIM + f] = ipq[((size_t)(b0 + b)*T_ENC + t)*18 + 1 + f];
    }
    sh_h[tid] = 0.f; sh_c[tid] = 0.f;
    if (tid < BBLK*T_ENC) {                       // label column of mid
        int b = tid / T_ENC, t = tid % T_ENC;
        sh_big[(b*T_ENC + t)*129 + 128] = labp[(size_t)(b0 + b)*T_ENC + t];
    }
    __syncthreads();
    for (int idx = tid; idx < BBLK*T_ENC*FDIM; idx += NTH) {   // pre1[b][s][f]
        int b = idx / (T_ENC*FDIM), r = idx % (T_ENC*FDIM), s = r / FDIM, f = r % FDIM;
        float acc = Ue1b[s];
        #pragma unroll 4
        for (int t = 0; t < T_ENC; ++t) acc = fmaf(sh_x[(b*T_ENC+t)*FDIM + f], Ue1W[s*T_ENC + t], acc);
        sh_p1[(b*T_ENC + s)*FDIM + f] = acc;
    }
    __syncthreads();

    // ============================ stage 1 ============================
    const float ve1b = Ve1b[0];
    for (int t = 0; t < T_ENC; ++t) {
        if (tid < BBLK*T_ENC) {                   // we[b][s] = [h,c] @ We1^T
            int b = tid / T_ENC, s = tid % T_ENC;
            const float* WT = ws + OFF_WE1T;
            float acc = 0.f;
            #pragma unroll 4
            for (int k = 0; k < H; ++k) {
                acc = fmaf(sh_h[b*H + k], WT[k*48 + s], acc);
                acc = fmaf(sh_c[b*H + k], WT[(H + k)*48 + s], acc);
            }
            sh_we[b*48 + s] = acc;
        }
        __syncthreads();
        if (tid < 272) {                          // score[b][f], 4 lanes per (b,f)
            int pair = tid >> 2, q = tid & 3, b = pair / FDIM, f = pair % FDIM;
            float acc = 0.f;
            for (int s = q; s < 48; s += 4)
                acc += fast_tanh(sh_we[b*48 + s] + sh_p1[(b*T_ENC + s)*FDIM + f]) * Ve1[s];
            acc += __shfl_xor(acc, 1);
            acc += __shfl_xor(acc, 2);
            if (q == 0) sh_sc[b*129 + f] = acc + ve1b;
        }
        __syncthreads();
        softmax4(sh_sc, sh_at, FDIM, tid);
        __syncthreads();
        for (int idx = tid; idx < BBLK*148; idx += NTH) {   // u = [x_t*attn, h, pad]
            int b = idx / 148, kk = idx % 148;
            float v;
            if (kk < FDIM)        v = sh_x[(b*T_ENC + t)*FDIM + kk] * sh_at[b*129 + kk];
            else if (kk < FDIM+H) v = sh_h[b*H + (kk - FDIM)];
            else                  v = 0.f;
            sh_u[b*260 + kk] = v;
        }
        __syncthreads();
        lstm_gates<37>((const float4*)(ws + OFF_WT1), ws + OFF_B1, sh_u, sh_g, tid);
        __syncthreads();
        {                                          // LSTM update + mid row
            int b = tid >> 7, jj = tid & 127;
            float gi = sh_g[b*512 + jj],       gf = sh_g[b*512 + 128 + jj];
            float gg = sh_g[b*512 + 256 + jj], go = sh_g[b*512 + 384 + jj];
            float c2 = fast_sigm(gf)*sh_c[tid] + fast_sigm(gi)*fast_tanh(gg);
            float hn = fast_sigm(go)*fast_tanh(c2);
            sh_c[tid] = c2; sh_h[tid] = hn;
            sh_big[(b*T_ENC + t)*129 + jj] = hn;
        }
        __syncthreads();
    }

    // ---- transition: pre2[b][s][f] -> ws; reset h,c ----
    for (int idx = tid; idx < BBLK*48*129; idx += NTH) {
        int b = idx / (48*129), r = idx % (48*129), s = r / 129, f = r % 129;
        float acc = Ue2b[s];
        #pragma unroll 4
        for (int t2 = 0; t2 < T_ENC; ++t2) acc = fmaf(sh_big[(b*T_ENC + t2)*129 + f], Ue2W[s*48 + t2], acc);
        ws[OFF_PRE2 + ((size_t)(b0 + b)*48 + s)*129 + f] = acc;
    }
    sh_h[tid] = 0.f; sh_c[tid] = 0.f;
    __syncthreads();

    // ============================ stage 2 ============================
    const float ve2b = Ve2b[0];
    const float* p2base = ws + OFF_PRE2 + (size_t)b0*48*129;
    for (int t = 0; t < T_ENC; ++t) {
        if (tid < BBLK*T_ENC) {
            int b = tid / T_ENC, s = tid % T_ENC;
            const float* WT = ws + OFF_WE2T;
            float acc = 0.f;
            #pragma unroll 4
            for (int k = 0; k < H; ++k) {
                acc = fmaf(sh_h[b*H + k], WT[k*48 + s], acc);
                acc = fmaf(sh_c[b*H + k], WT[(H + k)*48 + s], acc);
            }
            sh_we[b*48 + s] = acc;
        }
        __syncthreads();
        for (int idx = tid; idx < 516; idx += NTH) {        // score over 129 features
            int b = idx / 129, f = idx % 129;
            const float* p2 = p2base + (size_t)b*48*129 + f;
            float acc = 0.f;
            #pragma unroll 4
            for (int s = 0; s < 48; ++s)
                acc += fast_tanh(sh_we[b*48 + s] + p2[s*129]) * Ve2[s];
            sh_sc[b*129 + f] = acc + ve2b;
        }
        __syncthreads();
        softmax4(sh_sc, sh_at, 129, tid);
        __syncthreads();
        for (int idx = tid; idx < BBLK*260; idx += NTH) {   // u = [m_t*attn, h, pad]
            int b = idx / 260, kk = idx % 260;
            float v;
            if (kk < 129)      v = sh_big[(b*T_ENC + t)*129 + kk] * sh_at[b*129 + kk];
            else if (kk < 257) v = sh_h[b*H + (kk - 129)];
            else               v = 0.f;
            sh_u[idx] = v;
        }
        __syncthreads();
        lstm_gates<65>((const float4*)(ws + OFF_WT2), ws + OFF_B2, sh_u, sh_g, tid);
        __syncthreads();
        {
            int b = tid >> 7, jj = tid & 127;
            float gi = sh_g[b*512 + jj],       gf = sh_g[b*512 + 128 + jj];
            float gg = sh_g[b*512 + 256 + jj], go = sh_g[b*512 + 384 + jj];
            float c2 = fast_sigm(gf)*sh_c[tid] + fast_sigm(gi)*fast_tanh(gg);
            float hn = fast_sigm(go)*fast_tanh(c2);
            sh_c[tid] = c2; sh_h[tid] = hn;
            ws[OFF_FIN + ((size_t)(b0 + b)*48 + t)*128 + jj] = hn;
        }
        __syncthreads();
    }

    // ---- transition: ud[b][t][h] into sh_big (stride 129); reset h,c ----
    for (int idx = tid; idx < BBLK*12*128; idx += NTH) {    // 4 t-rows per thread (UdT reuse)
        int b = idx / (12*128), r = idx % (12*128), t4 = r >> 7, hh = r & 127;
        const float* fb = ws + OFF_FIN + ((size_t)(b0 + b)*48 + t4*4)*128;
        const float* UT = ws + OFF_UDT + hh;
        float ub = Udb[hh];
        float a0 = ub, a1 = ub, a2 = ub, a3 = ub;
        #pragma unroll 4
        for (int k = 0; k < 128; ++k) {
            float w = UT[k*128];
            a0 = fmaf(fb[k],       w, a0);
            a1 = fmaf(fb[128 + k], w, a1);
            a2 = fmaf(fb[256 + k], w, a2);
            a3 = fmaf(fb[384 + k], w, a3);
        }
        int tb = (b*T_ENC + t4*4)*129 + hh;
        sh_big[tb] = a0; sh_big[tb + 129] = a1; sh_big[tb + 258] = a2; sh_big[tb + 387] = a3;
    }
    sh_h[tid] = 0.f; sh_c[tid] = 0.f;
    __syncthreads();

    // ============================ decoder ============================
    const float vdb = Vdb[0], rb = regb[0];
    for (int st = 0; st < 30; ++st) {
        {                                          // wd[b][s'] all 512 threads
            int b = tid >> 7, sp = tid & 127;
            const float* WT = ws + OFF_WDT;
            float acc = 0.f;
            #pragma unroll 4
            for (int k = 0; k < H; ++k) {
                acc = fmaf(sh_h[b*H + k], WT[k*128 + sp], acc);
                acc = fmaf(sh_c[b*H + k], WT[(H + k)*128 + sp], acc);
            }
            sh_we[tid] = acc;
        }
        __syncthreads();
        if (tid < 384) {                           // score[b][t], 2 lanes per (b,t)
            int pair = tid >> 1, q = tid & 1, b = pair / 48, tt = pair % 48;
            float acc = 0.f;
            int h0 = q*64;
            for (int hh = h0; hh < h0 + 64; ++hh)
                acc += fast_tanh(sh_we[b*128 + hh] + sh_big[(b*T_ENC + tt)*129 + hh]) * Vd[hh];
            acc += __shfl_xor(acc, 1);
            if (q == 0) sh_sc[b*129 + tt] = acc + vdb;
        }
        __syncthreads();
        softmax4(sh_sc, sh_at, 48, tid);
        __syncthreads();
        {                                          // din[b][h] = attn @ fin ; build u
            int b = tid >> 7, hh = tid & 127;
            const float* fb = ws + OFF_FIN + (size_t)(b0 + b)*48*128 + hh;
            float acc = 0.f;
            #pragma unroll 4
            for (int tt = 0; tt < 48; ++tt) acc = fmaf(sh_at[b*129 + tt], fb[tt*128], acc);
            sh_u[b*260 + hh] = acc;
            sh_u[b*260 + 128 + hh] = sh_h[tid];
        }
        __syncthreads();
        lstm_gates<64>((const float4*)(ws + OFF_WTD), ws + OFF_BD, sh_u, sh_g, tid);
        __syncthreads();
        {
            int b = tid >> 7, jj = tid & 127;
            float gi = sh_g[b*512 + jj],       gf = sh_g[b*512 + 128 + jj];
            float gg = sh_g[b*512 + 256 + jj], go = sh_g[b*512 + 384 + jj];
            float c2 = fast_sigm(gf)*sh_c[tid] + fast_sigm(gi)*fast_tanh(gg);
            float hn = fast_sigm(go)*fast_tanh(c2);
            sh_c[tid] = c2; sh_h[tid] = hn;
        }
        __syncthreads();
        if (st >= 6 && tid < 256) {                // out[b][st-6] = h . regW + regb
            int b = tid >> 6, l = tid & 63;
            float v = sh_h[b*H + l]*regW[l] + sh_h[b*H + 64 + l]*regW[64 + l];
            for (int o = 32; o; o >>= 1) v += __shfl_xor(v, o);
            if (l == 0) out[(size_t)(b0 + b)*24 + (st - 6)] = v + rb;
        }
        // no barrier needed: next phase only reads sh_h (read-read with this block)
    }
}

extern "C" void kernel_launch(void* const* d_in, const int* in_sizes, int n_in,
                              void* d_out, int out_size, void* d_ws, size_t ws_size,
                              hipStream_t stream)
{
    const float* ipq   = (const float*)d_in[0];
    const float* labp  = (const float*)d_in[1];
    const float* Ue1W  = (const float*)d_in[2];
    const float* Ue1b  = (const float*)d_in[3];
    const float* We1W  = (const float*)d_in[4];
    const float* Ve1   = (const float*)d_in[5];
    const float* Ve1b  = (const float*)d_in[6];
    const float* Ue2W  = (const float*)d_in[7];
    const float* Ue2b  = (const float*)d_in[8];
    const float* We2W  = (const float*)d_in[9];
    const float* Ve2   = (const float*)d_in[10];
    const float* Ve2b  = (const float*)d_in[11];
    const float* UdW   = (const float*)d_in[12];
    const float* Udb   = (const float*)d_in[13];
    const float* WdW   = (const float*)d_in[14];
    const float* Vd    = (const float*)d_in[15];
    const float* Vdb   = (const float*)d_in[16];
    const float* e1Wih = (const float*)d_in[17];
    const float* e1Whh = (const float*)d_in[18];
    const float* e1bih = (const float*)d_in[19];
    const float* e1bhh = (const float*)d_in[20];
    const float* e2Wih = (const float*)d_in[21];
    const float* e2Whh = (const float*)d_in[22];
    const float* e2bih = (const float*)d_in[23];
    const float* e2bhh = (const float*)d_in[24];
    const float* dWih  = (const float*)d_in[25];
    const float* dWhh  = (const float*)d_in[26];
    const float* dbih  = (const float*)d_in[27];
    const float* dbhh  = (const float*)d_in[28];
    const float* regW  = (const float*)d_in[29];
    const float* regb  = (const float*)d_in[30];
    float* ws  = (float*)d_ws;
    float* out = (float*)d_out;

    prep_kernel<<<(415232 + 255)/256, 256, 0, stream>>>(
        We1W, We2W, WdW, UdW,
        e1Wih, e1Whh, e1bih, e1bhh,
        e2Wih, e2Whh, e2bih, e2bhh,
        dWih, dWhh, dbih, dbhh, ws);

    const size_t smem = 36952u * sizeof(float);   // 147,808 B dynamic LDS
    hipFuncSetAttribute((const void*)dstp_main,
                        hipFuncAttributeMaxDynamicSharedMemorySize, (int)smem);
    dstp_main<<<256, NTH, smem, stream>>>(
        ipq, labp, Ue1W, Ue1b, Ve1, Ve1b,
        Ue2W, Ue2b, Ve2, Ve2b,
        Udb, Vd, Vdb, regW, regb, ws, out);
}

// Round 4
// 2302.992 us; speedup vs baseline: 1.2364x; 1.2364x over previous
//
#include <hip/hip_runtime.h>

// DSTP-RNN: B=1024, T_ENC=48, 30 decoder steps, H=128, F=17.
// Round 4: round-3 structure with the stage-2 u-build coverage bug fixed
// (if(tid<520) with 512 threads left batch-1 u[252..259] uninitialized ->
// odd batches corrupted). Now a strided loop again.
// BBLK=2, 512 blocks, 2 blocks/CU (16 waves/CU), pre2/ud in LDS,
// mid/fin in ws, coalesced/broadcast access everywhere.

#define T_ENC 48
#define H 128
#define FDIM 17
#define BBLK 2
#define NTH 512
#define GRID 512

// ---- ws float offsets ----
#define OFF_WT1   0          // 148*512 = 75776   (e1 gate weights, [k4][j][4])
#define OFF_WT2   75776      // 260*512 = 133120  (e2)
#define OFF_WTD   208896     // 256*512 = 131072  (dec)
#define OFF_WE1T  339968     // 256*48  = 12288   (We1^T [k][s])
#define OFF_WE2T  352256     // 256*48  = 12288
#define OFF_WDT   364544     // 256*128 = 32768   (Wd^T [k][sp])
#define OFF_UDT   397312     // 128*128 = 16384   (Ud^T [k][h])
#define OFF_B1    413696     // 512 combined biases
#define OFF_B2    414208
#define OFF_BD    414720
#define OFF_MID   415232     // 1024*48*129, [b][t][129] (mid; reused as ud scratch)
#define OFF_FIN   6755840    // 1024*48*128, [b][t][h]

__device__ __forceinline__ float fast_sigm(float x){
    return __fdividef(1.0f, 1.0f + __expf(-x));
}
__device__ __forceinline__ float fast_tanh(float x){
    float xc = fminf(fmaxf(x, -9.0f), 9.0f);
    float e = __expf(2.0f * xc);
    return __fdividef(e - 1.0f, e + 1.0f);
}

// ---------------- prologue: transpose/fuse weights into ws ----------------
__global__ void prep_kernel(const float* __restrict__ We1W, const float* __restrict__ We2W,
                            const float* __restrict__ WdW,  const float* __restrict__ UdW,
                            const float* __restrict__ e1Wih, const float* __restrict__ e1Whh,
                            const float* __restrict__ e1bih, const float* __restrict__ e1bhh,
                            const float* __restrict__ e2Wih, const float* __restrict__ e2Whh,
                            const float* __restrict__ e2bih, const float* __restrict__ e2bhh,
                            const float* __restrict__ dWih,  const float* __restrict__ dWhh,
                            const float* __restrict__ dbih,  const float* __restrict__ dbhh,
                            float* __restrict__ ws)
{
    int idx = blockIdx.x * blockDim.x + threadIdx.x;
    if (idx < 75776) {                       // WT1 [k4][j][4]: k<17 Wih, k<145 Whh, else 0
        int k4 = idx >> 11, r = idx & 2047, j = r >> 2, kq = r & 3, k = k4*4 + kq;
        float v = 0.f;
        if (k < 17) v = e1Wih[j*17 + k]; else if (k < 145) v = e1Whh[j*128 + (k-17)];
        ws[OFF_WT1 + idx] = v; return;
    }
    idx -= 75776;
    if (idx < 133120) {                      // WT2: k<129 Wih, k<257 Whh
        int k4 = idx >> 11, r = idx & 2047, j = r >> 2, kq = r & 3, k = k4*4 + kq;
        float v = 0.f;
        if (k < 129) v = e2Wih[j*129 + k]; else if (k < 257) v = e2Whh[j*128 + (k-129)];
        ws[OFF_WT2 + idx] = v; return;
    }
    idx -= 133120;
    if (idx < 131072) {                      // WTD: k<128 Wih, else Whh
        int k4 = idx >> 11, r = idx & 2047, j = r >> 2, kq = r & 3, k = k4*4 + kq;
        float v = (k < 128) ? dWih[j*128 + k] : dWhh[j*128 + (k-128)];
        ws[OFF_WTD + idx] = v; return;
    }
    idx -= 131072;
    if (idx < 12288) { int k = idx/48, s = idx%48; ws[OFF_WE1T + idx] = We1W[s*256 + k]; return; }
    idx -= 12288;
    if (idx < 12288) { int k = idx/48, s = idx%48; ws[OFF_WE2T + idx] = We2W[s*256 + k]; return; }
    idx -= 12288;
    if (idx < 32768) { int k = idx>>7, s = idx&127; ws[OFF_WDT + idx] = WdW[s*256 + k]; return; }
    idx -= 32768;
    if (idx < 16384) { int k = idx>>7, hh = idx&127; ws[OFF_UDT + idx] = UdW[hh*128 + k]; return; }
    idx -= 16384;
    if (idx < 512) { ws[OFF_B1 + idx] = e1bih[idx] + e1bhh[idx]; return; }
    idx -= 512;
    if (idx < 512) { ws[OFF_B2 + idx] = e2bih[idx] + e2bhh[idx]; return; }
    idx -= 512;
    if (idx < 512) { ws[OFF_BD + idx] = dbih[idx] + dbhh[idx]; return; }
}

// gate matmul: g[b][j] = bias[j] + sum_k u[b][k]*W[k][j]; j = tid, 2 batches
template<int K4>
__device__ __forceinline__ void lstm_gates2(const float4* __restrict__ W4,
                                            const float* __restrict__ bias,
                                            const float* u, float* g, int tid)
{
    float bb = bias[tid];
    float a0 = bb, a1 = bb;
    #pragma unroll 4
    for (int k4 = 0; k4 < K4; ++k4) {
        float4 w  = W4[k4*512 + tid];
        float4 ua = *(const float4*)(u +       4*k4);
        float4 ub = *(const float4*)(u + 264 + 4*k4);
        a0 = fmaf(w.w, ua.w, fmaf(w.z, ua.z, fmaf(w.y, ua.y, fmaf(w.x, ua.x, a0))));
        a1 = fmaf(w.w, ub.w, fmaf(w.z, ub.z, fmaf(w.y, ub.y, fmaf(w.x, ub.x, a1))));
    }
    g[tid] = a0; g[512 + tid] = a1;
}

// softmax over n entries per batch row (2 rows), 32 threads per b, stride 129
__device__ __forceinline__ void softmax2(float* sc, float* at, int n, int tid)
{
    if (tid < 64) {
        int b = tid >> 5, i = tid & 31, base = b*129;
        float m = -1e30f;
        for (int f = i; f < n; f += 32) m = fmaxf(m, sc[base + f]);
        for (int o = 16; o; o >>= 1) m = fmaxf(m, __shfl_xor(m, o, 32));
        float ssum = 0.f;
        for (int f = i; f < n; f += 32) { float p = __expf(sc[base+f] - m); at[base+f] = p; ssum += p; }
        for (int o = 16; o; o >>= 1) ssum += __shfl_xor(ssum, o, 32);
        float inv = __fdividef(1.f, ssum);
        for (int f = i; f < n; f += 32) at[base + f] *= inv;
    }
}

// attention pre-projection we[b][s] = [h;c] @ W^T, 384 threads, quad split-K
__device__ __forceinline__ void we_phase(const float* __restrict__ WT,
                                         const float* sh_h, const float* sh_c,
                                         float* sh_we, int tid)
{
    if (tid < 384) {
        int b = tid / 192, r = tid % 192, s = r >> 2, kq = r & 3;
        const float* st = ((kq < 2) ? sh_h : sh_c) + b*H + (kq & 1)*64;
        const float* w  = WT + (kq*64)*48 + s;
        float acc = 0.f;
        #pragma unroll 8
        for (int kk = 0; kk < 64; ++kk)
            acc = fmaf(st[kk], w[kk*48], acc);
        acc += __shfl_xor(acc, 1);
        acc += __shfl_xor(acc, 2);
        if (kq == 0) sh_we[b*48 + s] = acc;
    }
}

__global__ __launch_bounds__(NTH, 4)
void dstp_main(const float* __restrict__ ipq,  const float* __restrict__ labp,
               const float* __restrict__ Ue1W, const float* __restrict__ Ue1b,
               const float* __restrict__ Ve1,  const float* __restrict__ Ve1b,
               const float* __restrict__ Ue2W, const float* __restrict__ Ue2b,
               const float* __restrict__ Ve2,  const float* __restrict__ Ve2b,
               const float* __restrict__ Udb,
               const float* __restrict__ Vd,   const float* __restrict__ Vdb,
               const float* __restrict__ regW, const float* __restrict__ regb,
               float* __restrict__ ws, float* __restrict__ out)
{
    extern __shared__ float sm[];
    float* sh_h   = sm;            // 256
    float* sh_c   = sm + 256;      // 256
    float* sh_we  = sm + 512;      // 256
    float* sh_sc  = sm + 768;      // 260 (stride 129)
    float* sh_at  = sm + 1028;     // 260
    float* sh_g   = sm + 1288;     // 1024 gates [2][512] / wd partials
    float* sh_u   = sm + 2312;     // 528 gate input [2][264], 16B aligned
    float* sh_x   = sm + 2840;     // 1632 x[2][48][17]
    float* sh_p1  = sm + 4472;     // 1632 pre1
    float* sh_big = sm + 6104;     // 12384: pre2 [2][48][129] / fin [2][48][128] / ud stride129
    // total 18488 floats = 73,952 B -> 2 blocks/CU

    const int tid = threadIdx.x;
    const int b0  = blockIdx.x * BBLK;

    // ---- phase 0 ----
    for (int idx = tid; idx < BBLK*T_ENC*FDIM; idx += NTH) {
        int b = idx / (T_ENC*FDIM), r = idx % (T_ENC*FDIM), t = r / FDIM, f = r % FDIM;
        sh_x[idx] = ipq[((size_t)(b0 + b)*T_ENC + t)*18 + 1 + f];
    }
    if (tid < 256) { sh_h[tid] = 0.f; sh_c[tid] = 0.f; }
    if (tid < BBLK*T_ENC) {                       // mid label column (f=128)
        int b = tid / T_ENC, t = tid % T_ENC;
        ws[OFF_MID + ((size_t)(b0 + b)*T_ENC + t)*129 + 128] = labp[(size_t)(b0 + b)*T_ENC + t];
    }
    __syncthreads();
    for (int idx = tid; idx < BBLK*T_ENC*FDIM; idx += NTH) {   // pre1[b][s][f]
        int b = idx / (T_ENC*FDIM), r = idx % (T_ENC*FDIM), s = r / FDIM, f = r % FDIM;
        float acc = Ue1b[s];
        #pragma unroll 4
        for (int t = 0; t < T_ENC; ++t) acc = fmaf(sh_x[(b*T_ENC+t)*FDIM + f], Ue1W[s*T_ENC + t], acc);
        sh_p1[(b*T_ENC + s)*FDIM + f] = acc;
    }
    __syncthreads();

    // ============================ stage 1 ============================
    const float ve1b = Ve1b[0];
    for (int t = 0; t < T_ENC; ++t) {
        we_phase(ws + OFF_WE1T, sh_h, sh_c, sh_we, tid);
        __syncthreads();
        if (tid < 136) {                          // score[b][f], 4 lanes per (b,f)
            int pair = tid >> 2, q = tid & 3, b = pair / FDIM, f = pair % FDIM;
            float acc = 0.f;
            for (int s = q; s < 48; s += 4)
                acc += fast_tanh(sh_we[b*48 + s] + sh_p1[(b*T_ENC + s)*FDIM + f]) * Ve1[s];
            acc += __shfl_xor(acc, 1);
            acc += __shfl_xor(acc, 2);
            if (q == 0) sh_sc[b*129 + f] = acc + ve1b;
        }
        __syncthreads();
        softmax2(sh_sc, sh_at, FDIM, tid);
        __syncthreads();
        if (tid < BBLK*148) {                     // u = [x_t*attn, h, pad]  (296 <= 512)
            int b = tid / 148, kk = tid % 148;
            float v;
            if (kk < FDIM)        v = sh_x[(b*T_ENC + t)*FDIM + kk] * sh_at[b*129 + kk];
            else if (kk < FDIM+H) v = sh_h[b*H + (kk - FDIM)];
            else                  v = 0.f;
            sh_u[b*264 + kk] = v;
        }
        __syncthreads();
        lstm_gates2<37>((const float4*)(ws + OFF_WT1), ws + OFF_B1, sh_u, sh_g, tid);
        __syncthreads();
        if (tid < 256) {                          // LSTM update + mid row -> ws
            int b = tid >> 7, jj = tid & 127;
            float gi = sh_g[b*512 + jj],       gf = sh_g[b*512 + 128 + jj];
            float gg = sh_g[b*512 + 256 + jj], go = sh_g[b*512 + 384 + jj];
            float c2 = fast_sigm(gf)*sh_c[tid] + fast_sigm(gi)*fast_tanh(gg);
            float hn = fast_sigm(go)*fast_tanh(c2);
            sh_c[tid] = c2; sh_h[tid] = hn;
            ws[OFF_MID + ((size_t)(b0 + b)*T_ENC + t)*129 + jj] = hn;
        }
        __syncthreads();
    }

    // ---- transition: pre2 -> LDS (sh_big), reset h,c ----
    for (int idx = tid; idx < BBLK*48*129; idx += NTH) {
        int b = idx / (48*129), r = idx % (48*129), s = r / 129, f = r % 129;
        const float* midb = ws + OFF_MID + (size_t)(b0 + b)*T_ENC*129 + f;
        float acc = Ue2b[s];
        #pragma unroll 4
        for (int t2 = 0; t2 < T_ENC; ++t2) acc = fmaf(midb[t2*129], Ue2W[s*48 + t2], acc);
        sh_big[(b*48 + s)*129 + f] = acc;
    }
    if (tid < 256) { sh_h[tid] = 0.f; sh_c[tid] = 0.f; }
    __syncthreads();

    // ============================ stage 2 ============================
    const float ve2b = Ve2b[0];
    for (int t = 0; t < T_ENC; ++t) {
        we_phase(ws + OFF_WE2T, sh_h, sh_c, sh_we, tid);
        __syncthreads();
        if (tid < 258) {                          // score over 129 f, pre2 from LDS
            int b = tid / 129, f = tid % 129;
            const float* p2 = sh_big + b*48*129 + f;
            const float* wv = sh_we + b*48;
            float acc = 0.f;
            #pragma unroll 4
            for (int s = 0; s < 48; ++s)
                acc += fast_tanh(wv[s] + p2[s*129]) * Ve2[s];
            sh_sc[b*129 + f] = acc + ve2b;
        }
        __syncthreads();
        softmax2(sh_sc, sh_at, 129, tid);
        __syncthreads();
        // FIX (round 4): BBLK*260 = 520 > NTH -> must be a strided loop, not if(tid<520).
        for (int idx = tid; idx < BBLK*260; idx += NTH) {   // u = [m_t*attn, h, pad]
            int b = idx / 260, kk = idx % 260;
            const float* midrow = ws + OFF_MID + ((size_t)(b0 + b)*T_ENC + t)*129;
            float v;
            if (kk < 129)      v = midrow[kk] * sh_at[b*129 + kk];
            else if (kk < 257) v = sh_h[b*H + (kk - 129)];
            else               v = 0.f;
            sh_u[b*264 + kk] = v;
        }
        __syncthreads();
        lstm_gates2<65>((const float4*)(ws + OFF_WT2), ws + OFF_B2, sh_u, sh_g, tid);
        __syncthreads();
        if (tid < 256) {
            int b = tid >> 7, jj = tid & 127;
            float gi = sh_g[b*512 + jj],       gf = sh_g[b*512 + 128 + jj];
            float gg = sh_g[b*512 + 256 + jj], go = sh_g[b*512 + 384 + jj];
            float c2 = fast_sigm(gf)*sh_c[tid] + fast_sigm(gi)*fast_tanh(gg);
            float hn = fast_sigm(go)*fast_tanh(c2);
            sh_c[tid] = c2; sh_h[tid] = hn;
            ws[OFF_FIN + ((size_t)(b0 + b)*T_ENC + t)*128 + jj] = hn;
        }
        __syncthreads();
    }

    // ---- transition: fin -> LDS, ud -> ws scratch -> LDS (stride 129) ----
    {
        const float4* fsrc = (const float4*)(ws + OFF_FIN + (size_t)b0*T_ENC*128);
        float4* fdst = (float4*)sh_big;
        for (int idx = tid; idx < BBLK*T_ENC*32; idx += NTH) fdst[idx] = fsrc[idx];
    }
    __syncthreads();
    {   // ud[b][t][h] = Udb[h] + fin[b][t][:] . UdT[:][h], 8 elems per chunk
        const int hh = tid & 127;
        const float* UT = ws + OFF_UDT + hh;
        float* uds = ws + OFF_MID + (size_t)b0*T_ENC*129;   // scratch (mid is dead), packed
        #pragma unroll
        for (int c = 0; c < 3; ++c) {
            float acc[8]; int rowb[8];
            #pragma unroll
            for (int i = 0; i < 8; ++i) {
                int idx = (c*8 + i)*NTH + tid;
                int b = idx / 6144, r = idx % 6144, tt = r >> 7;
                rowb[i] = (b*T_ENC + tt)*128;
                acc[i] = Udb[hh];
            }
            for (int k = 0; k < 128; ++k) {
                float w = UT[k*128];
                #pragma unroll
                for (int i = 0; i < 8; ++i) acc[i] = fmaf(sh_big[rowb[i] + k], w, acc[i]);
            }
            #pragma unroll
            for (int i = 0; i < 8; ++i) uds[(size_t)(c*8 + i)*NTH + tid] = acc[i];
        }
    }
    if (tid < 256) { sh_h[tid] = 0.f; sh_c[tid] = 0.f; }
    __syncthreads();
    {   // copy ud scratch into sh_big at stride 129
        const float* uds = ws + OFF_MID + (size_t)b0*T_ENC*129;
        for (int idx = tid; idx < BBLK*T_ENC*128; idx += NTH) {
            int b = idx / 6144, r = idx % 6144, tt = r >> 7, h2 = r & 127;
            sh_big[(b*T_ENC + tt)*129 + h2] = uds[idx];
        }
    }
    __syncthreads();

    // ============================ decoder ============================
    const float vdb = Vdb[0], rb = regb[0];
    const float* fing = ws + OFF_FIN + (size_t)b0*T_ENC*128;
    for (int st = 0; st < 30; ++st) {
        {   // wd partials: [b][kh][sp] -> sh_g, K split 2x128
            int b = tid >> 8, r = tid & 255, kh = r >> 7, sp = r & 127;
            const float* stv = (kh ? sh_c : sh_h) + b*H;
            const float* w   = ws + OFF_WDT + (kh*128)*128 + sp;
            float acc = 0.f;
            #pragma unroll 8
            for (int kk = 0; kk < 128; ++kk)
                acc = fmaf(stv[kk], w[kk*128], acc);
            sh_g[(b*2 + kh)*128 + sp] = acc;
        }
        __syncthreads();
        if (tid < 192) {                           // score[b][t], 2 lanes per (b,t)
            int q = tid & 1, pair = tid >> 1, b = pair / 48, tt = pair % 48;
            const float* pg = sh_g + b*256;
            float acc = 0.f;
            int h0 = q*64;
            #pragma unroll 4
            for (int kk = 0; kk < 64; ++kk) {
                int hh = h0 + kk;
                float wd = pg[hh] + pg[128 + hh];
                acc += fast_tanh(wd + sh_big[(b*T_ENC + tt)*129 + hh]) * Vd[hh];
            }
            acc += __shfl_xor(acc, 1);
            if (q == 0) sh_sc[b*129 + tt] = acc + vdb;
        }
        __syncthreads();
        softmax2(sh_sc, sh_at, 48, tid);
        __syncthreads();
        if (tid < 256) {                           // din[b][h] = attn @ fin; build u
            int b = tid >> 7, hh = tid & 127;
            const float* fb = fing + b*T_ENC*128 + hh;
            float acc = 0.f;
            #pragma unroll 4
            for (int tt = 0; tt < 48; ++tt) acc = fmaf(sh_at[b*129 + tt], fb[tt*128], acc);
            sh_u[b*264 + hh] = acc;
            sh_u[b*264 + 128 + hh] = sh_h[tid];
        }
        __syncthreads();
        lstm_gates2<64>((const float4*)(ws + OFF_WTD), ws + OFF_BD, sh_u, sh_g, tid);
        __syncthreads();
        if (tid < 256) {
            int b = tid >> 7, jj = tid & 127;
            float gi = sh_g[b*512 + jj],       gf = sh_g[b*512 + 128 + jj];
            float gg = sh_g[b*512 + 256 + jj], go = sh_g[b*512 + 384 + jj];
            float c2 = fast_sigm(gf)*sh_c[tid] + fast_sigm(gi)*fast_tanh(gg);
            float hn = fast_sigm(go)*fast_tanh(c2);
            sh_c[tid] = c2; sh_h[tid] = hn;
        }
        __syncthreads();
        if (st >= 6 && tid < 128) {                // out write (reads only sh_h)
            int b = tid >> 6, l = tid & 63;
            float v = sh_h[b*H + l]*regW[l] + sh_h[b*H + 64 + l]*regW[64 + l];
            for (int o = 32; o; o >>= 1) v += __shfl_xor(v, o);
            if (l == 0) out[(size_t)(b0 + b)*24 + (st - 6)] = v + rb;
        }
        // next wd phase only READS sh_h/sh_c -> no extra barrier needed
    }
}

extern "C" void kernel_launch(void* const* d_in, const int* in_sizes, int n_in,
                              void* d_out, int out_size, void* d_ws, size_t ws_size,
                              hipStream_t stream)
{
    const float* ipq   = (const float*)d_in[0];
    const float* labp  = (const float*)d_in[1];
    const float* Ue1W  = (const float*)d_in[2];
    const float* Ue1b  = (const float*)d_in[3];
    const float* We1W  = (const float*)d_in[4];
    const float* Ve1   = (const float*)d_in[5];
    const float* Ve1b  = (const float*)d_in[6];
    const float* Ue2W  = (const float*)d_in[7];
    const float* Ue2b  = (const float*)d_in[8];
    const float* We2W  = (const float*)d_in[9];
    const float* Ve2   = (const float*)d_in[10];
    const float* Ve2b  = (const float*)d_in[11];
    const float* UdW   = (const float*)d_in[12];
    const float* Udb   = (const float*)d_in[13];
    const float* WdW   = (const float*)d_in[14];
    const float* Vd    = (const float*)d_in[15];
    const float* Vdb   = (const float*)d_in[16];
    const float* e1Wih = (const float*)d_in[17];
    const float* e1Whh = (const float*)d_in[18];
    const float* e1bih = (const float*)d_in[19];
    const float* e1bhh = (const float*)d_in[20];
    const float* e2Wih = (const float*)d_in[21];
    const float* e2Whh = (const float*)d_in[22];
    const float* e2bih = (const float*)d_in[23];
    const float* e2bhh = (const float*)d_in[24];
    const float* dWih  = (const float*)d_in[25];
    const float* dWhh  = (const float*)d_in[26];
    const float* dbih  = (const float*)d_in[27];
    const float* dbhh  = (const float*)d_in[28];
    const float* regW  = (const float*)d_in[29];
    const float* regb  = (const float*)d_in[30];
    float* ws  = (float*)d_ws;
    float* out = (float*)d_out;

    prep_kernel<<<(415232 + 255)/256, 256, 0, stream>>>(
        We1W, We2W, WdW, UdW,
        e1Wih, e1Whh, e1bih, e1bhh,
        e2Wih, e2Whh, e2bih, e2bhh,
        dWih, dWhh, dbih, dbhh, ws);

    const size_t smem = 18488u * sizeof(float);   // 73,952 B -> 2 blocks/CU
    hipFuncSetAttribute((const void*)dstp_main,
                        hipFuncAttributeMaxDynamicSharedMemorySize, (int)smem);
    dstp_main<<<GRID, NTH, smem, stream>>>(
        ipq, labp, Ue1W, Ue1b, Ve1, Ve1b,
        Ue2W, Ue2b, Ve2, Ve2b,
        Udb, Vd, Vdb, regW, regb, ws, out);
}

// Round 5
// 1813.719 us; speedup vs baseline: 1.5699x; 1.2698x over previous
//
#include <hip/hip_runtime.h>

// DSTP-RNN: B=1024, T_ENC=48, 30 decoder steps, H=128, F=17.
// Round 5: fp16 weights + v_dot2_f32_f16 for all matmul phases; fp16 LDS for
// pre2/fin/ud (halves LDS -> 3 blocks/CU). fp32 state/accumulation everywhere.

#define T_ENC 48
#define H 128
#define FDIM 17
#define BBLK 2
#define NTH 512
#define GRID 512

// ---- ws HALF offsets (region starts at ws byte 0) ----
#define H_WT1   0          // 19*512*8  = 77824  (e1 gates, [k8][j][8h], K pad 152)
#define H_WT2   77824      // 33*512*8  = 135168 (e2, K pad 264)
#define H_WTD   212992     // 32*512*8  = 131072 (dec, K=256)
#define H_WE1T  344064     // 128*48*2  = 12288  (We1^T pairs [k2][s][2])
#define H_WE2T  356352     // 12288
#define H_WDT   368640     // 128*128*2 = 32768  (Wd^T pairs [k2][sp][2])
#define H_UDT   401408     // 64*128*2  = 16384  (Ud^T pairs [k2][h][2])
// halves end at 417792 -> 835584 B = 208896 floats
// ---- ws FLOAT offsets ----
#define F_B1    208896
#define F_B2    209408
#define F_BD    209920
#define F_MID   210432     // 1024*48*129 fp32 (mid; reused as ud scratch)
#define F_FIN   6551040    // 1024*48*128 fp32

typedef _Float16 h2_t __attribute__((ext_vector_type(2)));
union H2U { h2_t h; uint u; float f; };

__device__ __forceinline__ h2_t uh(uint v){ H2U x; x.u = v; return x.h; }
__device__ __forceinline__ h2_t fh(float v){ H2U x; x.f = v; return x.h; }
__device__ __forceinline__ uint pack2(float a, float b){
    H2U x; x.h[0] = (_Float16)a; x.h[1] = (_Float16)b; return x.u;
}
__device__ __forceinline__ float dot2f(h2_t a, h2_t b, float c){
#if __has_builtin(__builtin_amdgcn_fdot2)
    return __builtin_amdgcn_fdot2(a, b, c, false);
#else
    return c + (float)a[0]*(float)b[0] + (float)a[1]*(float)b[1];
#endif
}

__device__ __forceinline__ float fast_sigm(float x){
    return __fdividef(1.0f, 1.0f + __expf(-x));
}
__device__ __forceinline__ float fast_tanh(float x){
    float xc = fminf(fmaxf(x, -9.0f), 9.0f);
    float e = __expf(2.0f * xc);
    return __fdividef(e - 1.0f, e + 1.0f);
}

// ---------------- prologue: transpose/fuse weights into ws (fp16) ----------------
__global__ void prep_kernel(const float* __restrict__ We1W, const float* __restrict__ We2W,
                            const float* __restrict__ WdW,  const float* __restrict__ UdW,
                            const float* __restrict__ e1Wih, const float* __restrict__ e1Whh,
                            const float* __restrict__ e1bih, const float* __restrict__ e1bhh,
                            const float* __restrict__ e2Wih, const float* __restrict__ e2Whh,
                            const float* __restrict__ e2bih, const float* __restrict__ e2bhh,
                            const float* __restrict__ dWih,  const float* __restrict__ dWhh,
                            const float* __restrict__ dbih,  const float* __restrict__ dbhh,
                            float* __restrict__ ws)
{
    int idx = blockIdx.x * blockDim.x + threadIdx.x;
    _Float16* wsh = (_Float16*)ws;
    if (idx < 77824) {                       // WT1 [k8][j][8]: k<17 Wih, k<145 Whh, else 0
        int k8 = idx >> 12, r = idx & 4095, j = r >> 3, kq = r & 7, k = k8*8 + kq;
        float v = 0.f;
        if (k < 17) v = e1Wih[j*17 + k]; else if (k < 145) v = e1Whh[j*128 + (k-17)];
        wsh[H_WT1 + idx] = (_Float16)v; return;
    }
    idx -= 77824;
    if (idx < 135168) {                      // WT2: k<129 Wih, k<257 Whh, else 0 (pad 264)
        int k8 = idx >> 12, r = idx & 4095, j = r >> 3, kq = r & 7, k = k8*8 + kq;
        float v = 0.f;
        if (k < 129) v = e2Wih[j*129 + k]; else if (k < 257) v = e2Whh[j*128 + (k-129)];
        wsh[H_WT2 + idx] = (_Float16)v; return;
    }
    idx -= 135168;
    if (idx < 131072) {                      // WTD: k<128 Wih else Whh (K=256)
        int k8 = idx >> 12, r = idx & 4095, j = r >> 3, kq = r & 7, k = k8*8 + kq;
        float v = (k < 128) ? dWih[j*128 + k] : dWhh[j*128 + (k-128)];
        wsh[H_WTD + idx] = (_Float16)v; return;
    }
    idx -= 131072;
    if (idx < 12288) {                       // We1^T pairs: [k2][s][2]
        int pr = idx >> 1, p = idx & 1, k2 = pr / 48, s = pr % 48;
        wsh[H_WE1T + idx] = (_Float16)We1W[s*256 + 2*k2 + p]; return;
    }
    idx -= 12288;
    if (idx < 12288) {
        int pr = idx >> 1, p = idx & 1, k2 = pr / 48, s = pr % 48;
        wsh[H_WE2T + idx] = (_Float16)We2W[s*256 + 2*k2 + p]; return;
    }
    idx -= 12288;
    if (idx < 32768) {                       // Wd^T pairs: [k2][sp][2]
        int pr = idx >> 1, p = idx & 1, k2 = pr >> 7, sp = pr & 127;
        wsh[H_WDT + idx] = (_Float16)WdW[sp*256 + 2*k2 + p]; return;
    }
    idx -= 32768;
    if (idx < 16384) {                       // Ud^T pairs: [k2][h][2]
        int pr = idx >> 1, p = idx & 1, k2 = pr >> 7, hh = pr & 127;
        wsh[H_UDT + idx] = (_Float16)UdW[hh*128 + 2*k2 + p]; return;
    }
    idx -= 16384;
    if (idx < 512) { ws[F_B1 + idx] = e1bih[idx] + e1bhh[idx]; return; }
    idx -= 512;
    if (idx < 512) { ws[F_B2 + idx] = e2bih[idx] + e2bhh[idx]; return; }
    idx -= 512;
    if (idx < 512) { ws[F_BD + idx] = dbih[idx] + dbhh[idx]; return; }
}

// gate matmul via dot2: g[b][j] = bias[j] + sum_k u[b][k]*W[k][j]; j = tid
template<int K8>
__device__ __forceinline__ void lstm_gates2h(const float4* __restrict__ W8,
                                             const float* __restrict__ bias,
                                             const uint* u2, float* g, int tid)
{
    float a0 = bias[tid], a1 = a0;
    #pragma unroll 4
    for (int k8 = 0; k8 < K8; ++k8) {
        float4 w  = W8[k8*512 + tid];                  // 8 halves (weights k..k+7)
        float4 ua = *(const float4*)(u2 + 4*k8);       // 8 halves batch 0
        float4 ub = *(const float4*)(u2 + 132 + 4*k8); // 8 halves batch 1
        a0 = dot2f(fh(w.x), fh(ua.x), a0); a0 = dot2f(fh(w.y), fh(ua.y), a0);
        a0 = dot2f(fh(w.z), fh(ua.z), a0); a0 = dot2f(fh(w.w), fh(ua.w), a0);
        a1 = dot2f(fh(w.x), fh(ub.x), a1); a1 = dot2f(fh(w.y), fh(ub.y), a1);
        a1 = dot2f(fh(w.z), fh(ub.z), a1); a1 = dot2f(fh(w.w), fh(ub.w), a1);
    }
    g[tid] = a0; g[512 + tid] = a1;
}

// softmax over n entries per batch row (2 rows), 32 threads per b, stride 129
__device__ __forceinline__ void softmax2(float* sc, float* at, int n, int tid)
{
    if (tid < 64) {
        int b = tid >> 5, i = tid & 31, base = b*129;
        float m = -1e30f;
        for (int f = i; f < n; f += 32) m = fmaxf(m, sc[base + f]);
        for (int o = 16; o; o >>= 1) m = fmaxf(m, __shfl_xor(m, o, 32));
        float ssum = 0.f;
        for (int f = i; f < n; f += 32) { float p = __expf(sc[base+f] - m); at[base+f] = p; ssum += p; }
        for (int o = 16; o; o >>= 1) ssum += __shfl_xor(ssum, o, 32);
        float inv = __fdividef(1.f, ssum);
        for (int f = i; f < n; f += 32) at[base + f] *= inv;
    }
}

// we[b][s] = [h;c] @ W^T via dot2; 384 threads, quad split-K (64 k each = 32 pairs)
__device__ __forceinline__ void we_phase_h(const uint* __restrict__ W2,
                                           const uint* h2, const uint* c2,
                                           float* sh_we, int tid)
{
    if (tid < 384) {
        int b = tid / 192, r = tid % 192, s = r >> 2, kq = r & 3;
        const uint* st2 = ((kq < 2) ? h2 : c2) + b*64 + (kq & 1)*32;  // 32 pairs
        const uint* w2  = W2 + (kq*32)*48 + s;
        float acc = 0.f;
        #pragma unroll 8
        for (int kk = 0; kk < 32; ++kk)
            acc = dot2f(uh(st2[kk]), uh(w2[kk*48]), acc);
        acc += __shfl_xor(acc, 1);
        acc += __shfl_xor(acc, 2);
        if (kq == 0) sh_we[b*48 + s] = acc;
    }
}

__global__ __launch_bounds__(NTH, 6)
void dstp_main(const float* __restrict__ ipq,  const float* __restrict__ labp,
               const float* __restrict__ Ue1W, const float* __restrict__ Ue1b,
               const float* __restrict__ Ve1,  const float* __restrict__ Ve1b,
               const float* __restrict__ Ue2W, const float* __restrict__ Ue2b,
               const float* __restrict__ Ve2,  const float* __restrict__ Ve2b,
               const float* __restrict__ Udb,
               const float* __restrict__ Vd,   const float* __restrict__ Vdb,
               const float* __restrict__ regW, const float* __restrict__ regb,
               float* __restrict__ ws, float* __restrict__ out)
{
    extern __shared__ float sm[];
    float* sh_h   = sm;            // 256 fp32 state
    float* sh_c   = sm + 256;      // 256
    float* sh_we  = sm + 512;      // 256
    float* sh_sc  = sm + 768;      // 260 (stride 129)
    float* sh_at  = sm + 1028;     // 260
    float* sh_g   = sm + 1288;     // 1024 gates [2][512] / wd partials
    float* sh_x   = sm + 2312;     // 1632 x[2][48][17]
    float* sh_p1  = sm + 3944;     // 1632 pre1
    uint*  sh_h2u = (uint*)(sm + 5576);   // 128: h fp16 pairs [2][64]
    uint*  sh_c2u = (uint*)(sm + 5704);   // 128: c fp16 pairs
    uint*  sh_u2  = (uint*)(sm + 5832);   // 264: gate input fp16 [2][132] (16B aligned)
    _Float16* sh_bigh = (_Float16*)(sm + 6096); // 12480 halves: pre2/fin/ud [2][48][130]
    // total 12336 floats = 49,344 B -> 3 blocks/CU

    const int tid = threadIdx.x;
    const int b0  = blockIdx.x * BBLK;
    const _Float16* wsh = (const _Float16*)ws;

    // ---- phase 0 ----
    for (int idx = tid; idx < BBLK*T_ENC*FDIM; idx += NTH) {
        int b = idx / (T_ENC*FDIM), r = idx % (T_ENC*FDIM), t = r / FDIM, f = r % FDIM;
        sh_x[idx] = ipq[((size_t)(b0 + b)*T_ENC + t)*18 + 1 + f];
    }
    if (tid < 256) { sh_h[tid] = 0.f; sh_c[tid] = 0.f; }
    if (tid < 128) { sh_h2u[tid] = 0u; sh_c2u[tid] = 0u; }
    if (tid < BBLK*T_ENC) {                       // mid label column (f=128)
        int b = tid / T_ENC, t = tid % T_ENC;
        ws[F_MID + ((size_t)(b0 + b)*T_ENC + t)*129 + 128] = labp[(size_t)(b0 + b)*T_ENC + t];
    }
    __syncthreads();
    for (int idx = tid; idx < BBLK*T_ENC*FDIM; idx += NTH) {   // pre1[b][s][f] fp32
        int b = idx / (T_ENC*FDIM), r = idx % (T_ENC*FDIM), s = r / FDIM, f = r % FDIM;
        float acc = Ue1b[s];
        #pragma unroll 4
        for (int t = 0; t < T_ENC; ++t) acc = fmaf(sh_x[(b*T_ENC+t)*FDIM + f], Ue1W[s*T_ENC + t], acc);
        sh_p1[(b*T_ENC + s)*FDIM + f] = acc;
    }
    __syncthreads();

    // ============================ stage 1 ============================
    const float ve1b = Ve1b[0];
    for (int t = 0; t < T_ENC; ++t) {
        we_phase_h((const uint*)(wsh + H_WE1T), sh_h2u, sh_c2u, sh_we, tid);
        __syncthreads();
        if (tid < 136) {                          // score[b][f], 4 lanes per (b,f)
            int pair = tid >> 2, q = tid & 3, b = pair / FDIM, f = pair % FDIM;
            float acc = 0.f;
            for (int s = q; s < 48; s += 4)
                acc += fast_tanh(sh_we[b*48 + s] + sh_p1[(b*T_ENC + s)*FDIM + f]) * Ve1[s];
            acc += __shfl_xor(acc, 1);
            acc += __shfl_xor(acc, 2);
            if (q == 0) sh_sc[b*129 + f] = acc + ve1b;
        }
        __syncthreads();
        softmax2(sh_sc, sh_at, FDIM, tid);
        __syncthreads();
        if (tid < BBLK*152) {                     // u fp16 = [x_t*attn, h, pad] (304 thr)
            int b = tid / 152, kk = tid % 152;
            float v;
            if (kk < FDIM)        v = sh_x[(b*T_ENC + t)*FDIM + kk] * sh_at[b*129 + kk];
            else if (kk < FDIM+H) v = sh_h[b*H + (kk - FDIM)];
            else                  v = 0.f;
            float vnb = __shfl_xor(v, 1);
            if (!(tid & 1)) sh_u2[b*132 + (kk >> 1)] = pack2(v, vnb);
        }
        __syncthreads();
        lstm_gates2h<19>((const float4*)(wsh + H_WT1), ws + F_B1, sh_u2, sh_g, tid);
        __syncthreads();
        if (tid < 256) {                          // LSTM update + mid row -> ws
            int b = tid >> 7, jj = tid & 127;
            float gi = sh_g[b*512 + jj],       gf = sh_g[b*512 + 128 + jj];
            float gg = sh_g[b*512 + 256 + jj], go = sh_g[b*512 + 384 + jj];
            float c2v = fast_sigm(gf)*sh_c[tid] + fast_sigm(gi)*fast_tanh(gg);
            float hn  = fast_sigm(go)*fast_tanh(c2v);
            sh_c[tid] = c2v; sh_h[tid] = hn;
            ws[F_MID + ((size_t)(b0 + b)*T_ENC + t)*129 + jj] = hn;
            float hnb = __shfl_xor(hn, 1), cnb = __shfl_xor(c2v, 1);
            if (!(jj & 1)) {
                sh_h2u[b*64 + (jj >> 1)] = pack2(hn, hnb);
                sh_c2u[b*64 + (jj >> 1)] = pack2(c2v, cnb);
            }
        }
        __syncthreads();
    }

    // ---- transition: pre2 (fp16) -> LDS sh_bigh [b][s][130]; reset h,c ----
    for (int idx = tid; idx < BBLK*48*129; idx += NTH) {
        int b = idx / (48*129), r = idx % (48*129), s = r / 129, f = r % 129;
        const float* midb = ws + F_MID + (size_t)(b0 + b)*T_ENC*129 + f;
        float acc = Ue2b[s];
        #pragma unroll 4
        for (int t2 = 0; t2 < T_ENC; ++t2) acc = fmaf(midb[t2*129], Ue2W[s*48 + t2], acc);
        sh_bigh[(b*48 + s)*130 + f] = (_Float16)acc;
    }
    if (tid < 256) { sh_h[tid] = 0.f; sh_c[tid] = 0.f; }
    if (tid < 128) { sh_h2u[tid] = 0u; sh_c2u[tid] = 0u; }
    __syncthreads();

    // ============================ stage 2 ============================
    const float ve2b = Ve2b[0];
    for (int t = 0; t < T_ENC; ++t) {
        we_phase_h((const uint*)(wsh + H_WE2T), sh_h2u, sh_c2u, sh_we, tid);
        __syncthreads();
        if (tid < 258) {                          // score over 129 f, pre2 fp16 from LDS
            int b = tid / 129, f = tid % 129;
            const _Float16* p2 = sh_bigh + b*48*130 + f;
            const float* wv = sh_we + b*48;
            float acc = 0.f;
            #pragma unroll 4
            for (int s = 0; s < 48; ++s)
                acc += fast_tanh(wv[s] + (float)p2[s*130]) * Ve2[s];
            sh_sc[b*129 + f] = acc + ve2b;
        }
        __syncthreads();
        softmax2(sh_sc, sh_at, 129, tid);
        __syncthreads();
        for (int idx = tid; idx < BBLK*264; idx += NTH) {   // u fp16 = [m_t*attn, h, pad]
            int b = idx / 264, kk = idx % 264;
            const float* midrow = ws + F_MID + ((size_t)(b0 + b)*T_ENC + t)*129;
            float v;
            if (kk < 129)      v = midrow[kk] * sh_at[b*129 + kk];
            else if (kk < 257) v = sh_h[b*H + (kk - 129)];
            else               v = 0.f;
            float vnb = __shfl_xor(v, 1);
            if (!(idx & 1)) sh_u2[b*132 + ((kk) >> 1)] = pack2(v, vnb);
        }
        __syncthreads();
        lstm_gates2h<33>((const float4*)(wsh + H_WT2), ws + F_B2, sh_u2, sh_g, tid);
        __syncthreads();
        if (tid < 256) {
            int b = tid >> 7, jj = tid & 127;
            float gi = sh_g[b*512 + jj],       gf = sh_g[b*512 + 128 + jj];
            float gg = sh_g[b*512 + 256 + jj], go = sh_g[b*512 + 384 + jj];
            float c2v = fast_sigm(gf)*sh_c[tid] + fast_sigm(gi)*fast_tanh(gg);
            float hn  = fast_sigm(go)*fast_tanh(c2v);
            sh_c[tid] = c2v; sh_h[tid] = hn;
            ws[F_FIN + ((size_t)(b0 + b)*T_ENC + t)*128 + jj] = hn;
            float hnb = __shfl_xor(hn, 1), cnb = __shfl_xor(c2v, 1);
            if (!(jj & 1)) {
                sh_h2u[b*64 + (jj >> 1)] = pack2(hn, hnb);
                sh_c2u[b*64 + (jj >> 1)] = pack2(c2v, cnb);
            }
        }
        __syncthreads();
    }

    // ---- transition: fin -> LDS fp16 pairs; ud -> ws scratch -> LDS fp16 ----
    {
        uint* fin2 = (uint*)sh_bigh;              // [b*48+t][64] pairs along h
        const float4* fsrc = (const float4*)(ws + F_FIN + (size_t)b0*T_ENC*128);
        for (int idx = tid; idx < BBLK*T_ENC*32; idx += NTH) {
            float4 v = fsrc[idx];
            fin2[2*idx]     = pack2(v.x, v.y);
            fin2[2*idx + 1] = pack2(v.z, v.w);
        }
    }
    __syncthreads();
    {   // ud[b][t][h] = Udb[h] + fin[b][t][:] . UdT[:][h] via dot2 (64 pairs)
        const int hh = tid & 127;
        const uint* UT2  = (const uint*)(wsh + H_UDT);
        const uint* fin2 = (const uint*)sh_bigh;
        float* uds = ws + F_MID + (size_t)b0*T_ENC*129;   // scratch (mid is dead), packed
        #pragma unroll
        for (int c = 0; c < 3; ++c) {
            float acc[8]; int rowb2[8];
            #pragma unroll
            for (int i = 0; i < 8; ++i) {
                int idx = (c*8 + i)*NTH + tid;
                int b = idx / 6144, r = idx % 6144, tt = r >> 7;
                rowb2[i] = (b*T_ENC + tt)*64;
                acc[i] = Udb[hh];
            }
            for (int k2 = 0; k2 < 64; ++k2) {
                h2_t w2 = uh(UT2[k2*128 + hh]);
                #pragma unroll
                for (int i = 0; i < 8; ++i) acc[i] = dot2f(uh(fin2[rowb2[i] + k2]), w2, acc[i]);
            }
            #pragma unroll
            for (int i = 0; i < 8; ++i) uds[(size_t)(c*8 + i)*NTH + tid] = acc[i];
        }
    }
    if (tid < 256) { sh_h[tid] = 0.f; sh_c[tid] = 0.f; }
    if (tid < 128) { sh_h2u[tid] = 0u; sh_c2u[tid] = 0u; }
    __syncthreads();
    {   // ud scratch -> sh_bigh fp16 at [b][t][130] (overwrites fin2; fin2 dead)
        const float* uds = ws + F_MID + (size_t)b0*T_ENC*129;
        for (int idx = tid; idx < BBLK*T_ENC*128; idx += NTH) {
            int b = idx / 6144, r = idx % 6144, tt = r >> 7, h2i = r & 127;
            sh_bigh[(b*T_ENC + tt)*130 + h2i] = (_Float16)uds[idx];
        }
    }
    __syncthreads();

    // ============================ decoder ============================
    const float vdb = Vdb[0], rb = regb[0];
    const float* fing = ws + F_FIN + (size_t)b0*T_ENC*128;
    for (int st = 0; st < 30; ++st) {
        {   // wd partials via dot2: [b][kh][sp] -> sh_g, K split h|c (64 pairs each)
            int b = tid >> 8, r = tid & 255, kh = r >> 7, sp = r & 127;
            const uint* st2 = (kh ? sh_c2u : sh_h2u) + b*64;
            const uint* W2  = (const uint*)(wsh + H_WDT) + (kh*64)*128 + sp;
            float acc = 0.f;
            #pragma unroll 8
            for (int kk = 0; kk < 64; ++kk)
                acc = dot2f(uh(st2[kk]), uh(W2[kk*128]), acc);
            sh_g[(b*2 + kh)*128 + sp] = acc;
        }
        __syncthreads();
        if (tid < 192) {                           // score[b][t], 2 lanes per (b,t)
            int q = tid & 1, pair = tid >> 1, b = pair / 48, tt = pair % 48;
            const float* pg = sh_g + b*256;
            const _Float16* udrow = sh_bigh + (b*T_ENC + tt)*130;
            float acc = 0.f;
            int h0 = q*64;
            #pragma unroll 4
            for (int kk = 0; kk < 64; ++kk) {
                int hh = h0 + kk;
                float wd = pg[hh] + pg[128 + hh];
                acc += fast_tanh(wd + (float)udrow[hh]) * Vd[hh];
            }
            acc += __shfl_xor(acc, 1);
            if (q == 0) sh_sc[b*129 + tt] = acc + vdb;
        }
        __syncthreads();
        softmax2(sh_sc, sh_at, 48, tid);
        __syncthreads();
        if (tid < 256) {                           // din[b][h] fp32 from ws fin; pack u
            int b = tid >> 7, hh = tid & 127;
            const float* fb = fing + b*T_ENC*128 + hh;
            float acc = 0.f;
            #pragma unroll 4
            for (int tt = 0; tt < 48; ++tt) acc = fmaf(sh_at[b*129 + tt], fb[tt*128], acc);
            float anb = __shfl_xor(acc, 1);
            if (!(hh & 1)) sh_u2[b*132 + (hh >> 1)] = pack2(acc, anb);
        }
        if (tid < 128) {                           // u[128..255] = h pairs (already packed)
            int b = tid >> 6, i = tid & 63;
            sh_u2[b*132 + 64 + i] = sh_h2u[b*64 + i];
        }
        __syncthreads();
        lstm_gates2h<32>((const float4*)(wsh + H_WTD), ws + F_BD, sh_u2, sh_g, tid);
        __syncthreads();
        if (tid < 256) {
            int b = tid >> 7, jj = tid & 127;
            float gi = sh_g[b*512 + jj],       gf = sh_g[b*512 + 128 + jj];
            float gg = sh_g[b*512 + 256 + jj], go = sh_g[b*512 + 384 + jj];
            float c2v = fast_sigm(gf)*sh_c[tid] + fast_sigm(gi)*fast_tanh(gg);
            float hn  = fast_sigm(go)*fast_tanh(c2v);
            sh_c[tid] = c2v; sh_h[tid] = hn;
            float hnb = __shfl_xor(hn, 1), cnb = __shfl_xor(c2v, 1);
            if (!(jj & 1)) {
                sh_h2u[b*64 + (jj >> 1)] = pack2(hn, hnb);
                sh_c2u[b*64 + (jj >> 1)] = pack2(c2v, cnb);
            }
        }
        __syncthreads();
        if (st >= 6 && tid < 128) {                // out write (reads only sh_h)
            int b = tid >> 6, l = tid & 63;
            float v = sh_h[b*H + l]*regW[l] + sh_h[b*H + 64 + l]*regW[64 + l];
            for (int o = 32; o; o >>= 1) v += __shfl_xor(v, o);
            if (l == 0) out[(size_t)(b0 + b)*24 + (st - 6)] = v + rb;
        }
        // next wd phase only READS h2/c2 (written before last barrier) -> safe
    }
}

extern "C" void kernel_launch(void* const* d_in, const int* in_sizes, int n_in,
                              void* d_out, int out_size, void* d_ws, size_t ws_size,
                              hipStream_t stream)
{
    const float* ipq   = (const float*)d_in[0];
    const float* labp  = (const float*)d_in[1];
    const float* Ue1W  = (const float*)d_in[2];
    const float* Ue1b  = (const float*)d_in[3];
    const float* We1W  = (const float*)d_in[4];
    const float* Ve1   = (const float*)d_in[5];
    const float* Ve1b  = (const float*)d_in[6];
    const float* Ue2W  = (const float*)d_in[7];
    const float* Ue2b  = (const float*)d_in[8];
    const float* We2W  = (const float*)d_in[9];
    const float* Ve2   = (const float*)d_in[10];
    const float* Ve2b  = (const float*)d_in[11];
    const float* UdW   = (const float*)d_in[12];
    const float* Udb   = (const float*)d_in[13];
    const float* WdW   = (const float*)d_in[14];
    const float* Vd    = (const float*)d_in[15];
    const float* Vdb   = (const float*)d_in[16];
    const float* e1Wih = (const float*)d_in[17];
    const float* e1Whh = (const float*)d_in[18];
    const float* e1bih = (const float*)d_in[19];
    const float* e1bhh = (const float*)d_in[20];
    const float* e2Wih = (const float*)d_in[21];
    const float* e2Whh = (const float*)d_in[22];
    const float* e2bih = (const float*)d_in[23];
    const float* e2bhh = (const float*)d_in[24];
    const float* dWih  = (const float*)d_in[25];
    const float* dWhh  = (const float*)d_in[26];
    const float* dbih  = (const float*)d_in[27];
    const float* dbhh  = (const float*)d_in[28];
    const float* regW  = (const float*)d_in[29];
    const float* regb  = (const float*)d_in[30];
    float* ws  = (float*)d_ws;
    float* out = (float*)d_out;

    // weights: 417792 halves; biases: 1536 floats
    prep_kernel<<<(417792 + 1536 + 255)/256, 256, 0, stream>>>(
        We1W, We2W, WdW, UdW,
        e1Wih, e1Whh, e1bih, e1bhh,
        e2Wih, e2Whh, e2bih, e2bhh,
        dWih, dWhh, dbih, dbhh, ws);

    const size_t smem = 12336u * sizeof(float);   // 49,344 B -> 3 blocks/CU
    hipFuncSetAttribute((const void*)dstp_main,
                        hipFuncAttributeMaxDynamicSharedMemorySize, (int)smem);
    dstp_main<<<GRID, NTH, smem, stream>>>(
        ipq, labp, Ue1W, Ue1b, Ve1, Ve1b,
        Ue2W, Ue2b, Ve2, Ve2b,
        Udb, Vd, Vdb, regW, regb, ws, out);
}